// Round 12
// baseline (238.276 us; speedup 1.0000x reference)
//
#include <hip/hip_runtime.h>

// GCN 2-layer forward for MI355X.
// out = D^-1/2 (A+I) D^-1/2 (X W) + b, twice, relu between.
// g = (X W) * dinv ; tmp[c] = g[c] + sum_{e: col_e=c} g[row_e] ; out = tmp*dinv + b.
// R2: CSR gather. R4: g bf16. R5: MFMA split-bf16 GEMM. R6-R8: bucketed CSR build.
// R9: XCD slicing FAILED. R10: scalar-addressed gather, packed edges.
// R11: bf16 h2 + nt stores (FETCH 109->80MB, dur flat -> gather at compulsory
//      per-XCD traffic floor; only work-elimination helps now).
// R12: fuse layer-2 GEMM into gather128 via LDS (h2 never touches global:
//      saves 12.8MB write + 12.8MB read + a launch); revert srow nt-load.

constexpr int KD = 128;      // inner dim of both GEMMs (Fin = Fh = 128)
constexpr int CHUNK = 4096;  // edges per block in scatter pass
constexpr int BCAP = 6144;   // slack capacity per bucket (mean 4096, sigma ~64)

using short8  = __attribute__((ext_vector_type(8))) short;
using float4v = __attribute__((ext_vector_type(4))) float;

// ---------------- bf16 helpers (storage = ushort, math = fp32) ----------------

__device__ __forceinline__ unsigned short f2bf(float f) {
    unsigned int u = __float_as_uint(f);
    u = (u + 0x7fffu + ((u >> 16) & 1u)) >> 16;  // round-to-nearest-even
    return (unsigned short)u;
}

__device__ __forceinline__ float2 bfpair(unsigned int u) {
    float2 f;
    f.x = __uint_as_float(u << 16);          // low short = first feature
    f.y = __uint_as_float(u & 0xffff0000u);  // high short = second feature
    return f;
}

__device__ __forceinline__ unsigned int packbf(float x, float y) {
    return (unsigned int)f2bf(x) | ((unsigned int)f2bf(y) << 16);
}

// split x = hi + lo (both bf16); subtraction is exact, |err| ~ 2^-17 |x|
__device__ __forceinline__ void bfsplit(float x, unsigned short& h, unsigned short& l) {
    h = f2bf(x);
    float fh = __uint_as_float((unsigned int)h << 16);
    l = f2bf(x - fh);
}

// ---------------- setup: W transpose+split (both layers) + gcur init ----------
__global__ __launch_bounds__(128) void setup(const float* __restrict__ W1,
                                             unsigned short* __restrict__ Wth1,
                                             unsigned short* __restrict__ Wtl1,
                                             const float* __restrict__ W2,
                                             unsigned short* __restrict__ Wth2,
                                             unsigned short* __restrict__ Wtl2,
                                             int* __restrict__ gcur) {
    int b = blockIdx.x;
    int n = threadIdx.x;
    int k = b & 127;
    if (b == 0) {
        gcur[n] = n * BCAP;
        gcur[n + 128] = (n + 128) * BCAP;
    }
    if (b < 128) {
        float w = W1[k * 128 + n];
        unsigned short h, l;
        bfsplit(w, h, l);
        Wth1[n * KD + k] = h;
        Wtl1[n * KD + k] = l;
    } else if (n < 64) {
        float w = W2[k * 64 + n];
        unsigned short h, l;
        bfsplit(w, h, l);
        Wth2[n * KD + k] = h;
        Wtl2[n * KD + k] = l;
    }
}

// ---------------- CSR build ----------------

// Edge scatter into slack buckets (by col>>8). Packed record: (row<<16)|col.
__global__ __launch_bounds__(256) void bucket_scatter(const int* __restrict__ row,
                                                      const int* __restrict__ col,
                                                      int* gcur,
                                                      unsigned int* __restrict__ bpack,
                                                      int E) {
    __shared__ int lh[256];
    __shared__ int lbase[256];
    lh[threadIdx.x] = 0;
    __syncthreads();
    int base = blockIdx.x * CHUNK;
#pragma unroll
    for (int r = 0; r < CHUNK / 256; ++r) {
        int e = base + r * 256 + threadIdx.x;
        if (e < E) atomicAdd(&lh[col[e] >> 8], 1);
    }
    __syncthreads();
    int c0 = lh[threadIdx.x];
    lbase[threadIdx.x] = c0 ? atomicAdd(&gcur[threadIdx.x], c0) : 0;
    __syncthreads();
    lh[threadIdx.x] = 0;  // reuse as local running offset
    __syncthreads();
#pragma unroll
    for (int r = 0; r < CHUNK / 256; ++r) {
        int e = base + r * 256 + threadIdx.x;
        if (e < E) {
            int c = col[e];
            int b = c >> 8;
            int slot = lbase[b] + atomicAdd(&lh[b], 1);
            bpack[slot] = ((unsigned int)row[e] << 16) | (unsigned int)c;
        }
    }
}

// One block per bucket: recompute bucket-count scan in LDS, node hist -> scan
// -> rowptr/dinv/srow. Bucket-major + node-within-bucket order IS CSR order.
__global__ __launch_bounds__(256) void bucket_csr(const unsigned int* __restrict__ bpack,
                                                  const int* __restrict__ gcur,
                                                  int* __restrict__ rowptr,
                                                  float* __restrict__ dinv,
                                                  unsigned short* __restrict__ srow,
                                                  int N, int E) {
    __shared__ int s[256];
    __shared__ int lh[256];
    __shared__ int lcur[256];
    __shared__ int sh_bstart;
    int b = blockIdx.x;
    int t = threadIdx.x;
    int cntb = gcur[t] - t * BCAP;
    s[t] = cntb;
    __syncthreads();
    for (int off = 1; off < 256; off <<= 1) {
        int tv = (t >= off) ? s[t - off] : 0;
        __syncthreads();
        s[t] += tv;
        __syncthreads();
    }
    if (t == b) sh_bstart = s[t] - cntb;  // exclusive prefix of this bucket
    if (b == 0 && t == 0) rowptr[N] = E;
    lh[t] = 0;
    __syncthreads();
    int bstart = sh_bstart;
    int nE = gcur[b] - b * BCAP;
    int base = b * BCAP;
    for (int i = t; i < nE; i += 256)
        atomicAdd(&lh[bpack[base + i] & 255], 1);
    __syncthreads();
    int v = lh[t];
    s[t] = v;
    __syncthreads();
    for (int off = 1; off < 256; off <<= 1) {
        int tv = (t >= off) ? s[t - off] : 0;
        __syncthreads();
        s[t] += tv;
        __syncthreads();
    }
    int myStart = bstart + s[t] - v;  // exclusive
    int node = (b << 8) + t;
    if (node < N) {
        rowptr[node] = myStart;
        dinv[node] = rsqrtf(1.0f + (float)v);
    }
    lcur[t] = myStart;
    __syncthreads();
    for (int i = t; i < nE; i += 256) {
        unsigned int p = bpack[base + i];
        int slot = atomicAdd(&lcur[p & 255], 1);
        srow[slot] = (unsigned short)(p >> 16);
    }
}

// -------- layer-1 GEMM (fp32 in): G = bf16(dinv*(X@W)), split A, 3 MFMAs -----
__global__ __launch_bounds__(256) void gemm_mfma1(const float* __restrict__ X,
                                                  const unsigned short* __restrict__ Wth,
                                                  const unsigned short* __restrict__ Wtl,
                                                  const float* __restrict__ dinv,
                                                  unsigned short* __restrict__ G, int N) {
    constexpr int FOUT = 128, NT = 8;
    int wave = threadIdx.x >> 6;
    int lane = threadIdx.x & 63;
    int row0 = (blockIdx.x * 4 + wave) * 16;
    if (row0 >= N) return;
    int m = lane & 15;
    int quad = lane >> 4;

    float4v acc[NT];
#pragma unroll
    for (int ct = 0; ct < NT; ++ct) acc[ct] = (float4v){0.f, 0.f, 0.f, 0.f};

    const float* xrow = X + (size_t)(row0 + m) * KD + quad * 8;

#pragma unroll
    for (int ks = 0; ks < 4; ++ks) {
        float4 xa = *(const float4*)(xrow + ks * 32);
        float4 xb = *(const float4*)(xrow + ks * 32 + 4);
        float xs[8] = {xa.x, xa.y, xa.z, xa.w, xb.x, xb.y, xb.z, xb.w};
        short8 ah, al;
#pragma unroll
        for (int j = 0; j < 8; ++j) {
            unsigned short h, l;
            bfsplit(xs[j], h, l);
            ah[j] = (short)h;
            al[j] = (short)l;
        }
        int koff = ks * 32 + quad * 8;
#pragma unroll
        for (int ct = 0; ct < NT; ++ct) {
            const unsigned short* wb = Wth + (size_t)(ct * 16 + m) * KD + koff;
            const unsigned short* wl = Wtl + (size_t)(ct * 16 + m) * KD + koff;
            short8 bh = *(const short8*)wb;
            short8 bl = *(const short8*)wl;
            acc[ct] = __builtin_amdgcn_mfma_f32_16x16x32_bf16(ah, bh, acc[ct], 0, 0, 0);
            acc[ct] = __builtin_amdgcn_mfma_f32_16x16x32_bf16(al, bh, acc[ct], 0, 0, 0);
            acc[ct] = __builtin_amdgcn_mfma_f32_16x16x32_bf16(ah, bl, acc[ct], 0, 0, 0);
        }
    }

#pragma unroll
    for (int r = 0; r < 4; ++r) {
        int row = row0 + quad * 4 + r;
        float s = dinv[row];
#pragma unroll
        for (int ct = 0; ct < NT; ++ct) {
            G[(size_t)row * FOUT + ct * 16 + m] = f2bf(acc[ct][r] * s);
        }
    }
}

// ------- FUSED: gather layer-1 (4 nodes/block, wave per node) + layer-2 GEMM -
// Gather phase: wave w aggregates node n=blk*4+w into h (bf16x2 per lane),
// stages into LDS. GEMM phase: wave 0 computes g2[n0..n0+3][0..63] =
// bf16(dinv * (H @ W2)) with 16x16x32 MFMAs (A rows 0..3 valid; D row m depends
// only on A row m, so rows 4..15 are don't-care). h2 never touches global.
__global__ __launch_bounds__(256) void gather_gemm2(const int* __restrict__ rowptr,
                                                    const unsigned short* __restrict__ srow,
                                                    const unsigned int* __restrict__ G,  // g1 bf16x2
                                                    const float* __restrict__ dinv,
                                                    const float* __restrict__ bias,    // b1
                                                    const unsigned short* __restrict__ Wth,  // W2 hi [n][k]
                                                    const unsigned short* __restrict__ Wtl,  // W2 lo [n][k]
                                                    unsigned short* __restrict__ G2,   // g2 bf16 [N][64]
                                                    int N) {
    __shared__ unsigned int Hs[4][64];  // 4 nodes x 128 feats bf16 (as bf16x2) = 1KB
    int wave = threadIdx.x >> 6;
    int lane = threadIdx.x & 63;
    int node0 = blockIdx.x * 4;
    int node = node0 + wave;

    if (node < N) {
        int beg = rowptr[node];
        int end = rowptr[node + 1];
        float ax, ay;
        {
            float2 s0 = bfpair(G[(size_t)node * 64 + lane]);  // self-loop
            ax = s0.x; ay = s0.y;
        }
        int e = beg;
        for (; e + 7 < end; e += 8) {
            unsigned int u[8];
#pragma unroll
            for (int j = 0; j < 8; ++j) {
                int r = __builtin_amdgcn_readfirstlane((int)srow[e + j]);
                const unsigned int* p = G + (size_t)r * 64;  // uniform base (SGPR)
                u[j] = p[lane];
            }
            float sx = 0.f, sy = 0.f;
#pragma unroll
            for (int j = 0; j < 8; ++j) {
                float2 v = bfpair(u[j]);
                sx += v.x; sy += v.y;
            }
            ax += sx; ay += sy;
        }
        for (; e < end; ++e) {
            int r = __builtin_amdgcn_readfirstlane((int)srow[e]);
            const unsigned int* p = G + (size_t)r * 64;
            float2 v = bfpair(p[lane]);
            ax += v.x; ay += v.y;
        }
        float s = dinv[node];
        float2 bv = ((const float2*)bias)[lane];
        float ox = fmaxf(ax * s + bv.x, 0.f);  // relu (layer 1)
        float oy = fmaxf(ay * s + bv.y, 0.f);
        Hs[wave][lane] = packbf(ox, oy);
    }
    __syncthreads();

    if (wave == 0) {
        int m = lane & 15;
        int quad = lane >> 4;
        float4v acc[4];
#pragma unroll
        for (int ct = 0; ct < 4; ++ct) acc[ct] = (float4v){0.f, 0.f, 0.f, 0.f};
        const unsigned short* hrow = (const unsigned short*)Hs[m & 3];  // rows 4..15 alias (don't-care)
#pragma unroll
        for (int ks = 0; ks < 4; ++ks) {
            int koff = ks * 32 + quad * 8;
            short8 a = *(const short8*)(hrow + koff);
#pragma unroll
            for (int ct = 0; ct < 4; ++ct) {
                short8 bh = *(const short8*)(Wth + (size_t)(ct * 16 + m) * KD + koff);
                short8 bl = *(const short8*)(Wtl + (size_t)(ct * 16 + m) * KD + koff);
                acc[ct] = __builtin_amdgcn_mfma_f32_16x16x32_bf16(a, bh, acc[ct], 0, 0, 0);
                acc[ct] = __builtin_amdgcn_mfma_f32_16x16x32_bf16(a, bl, acc[ct], 0, 0, 0);
            }
        }
        // D row = quad*4 + r; only quad==0 lanes hold rows 0..3 (= nodes)
        if (quad == 0) {
#pragma unroll
            for (int r = 0; r < 4; ++r) {
                int nd = node0 + r;
                if (nd < N) {
                    float s = dinv[nd];
#pragma unroll
                    for (int ct = 0; ct < 4; ++ct) {
                        G2[(size_t)nd * 64 + ct * 16 + m] = f2bf(acc[ct][r] * s);
                    }
                }
            }
        }
    }
}

// F=64 gather: half-wave per node (32 lanes x bf16x2 = 128B row), fp32 nt out.
template <bool RELU>
__global__ __launch_bounds__(256) void gather64(const int* __restrict__ rowptr,
                                                const unsigned short* __restrict__ srow,
                                                const unsigned int* __restrict__ G,  // bf16x2
                                                const float* __restrict__ dinv,
                                                const float* __restrict__ bias,
                                                float* __restrict__ O, int N) {
    int tid = blockIdx.x * 256 + threadIdx.x;
    int node = tid >> 5;          // half-wave per node
    int lane = threadIdx.x & 31;
    if (node >= N) return;
    int beg = rowptr[node];
    int end = rowptr[node + 1];

    float2 s0 = bfpair(G[(size_t)node * 32 + lane]);  // self-loop
    float ax = s0.x, ay = s0.y;

    int e = beg;
    for (; e + 7 < end; e += 8) {
        unsigned int u[8];
#pragma unroll
        for (int j = 0; j < 8; ++j) {
            int r = (int)srow[e + j];
            u[j] = G[(size_t)r * 32 + lane];
        }
        float sx = 0.f, sy = 0.f;
#pragma unroll
        for (int j = 0; j < 8; ++j) {
            float2 v = bfpair(u[j]);
            sx += v.x; sy += v.y;
        }
        ax += sx; ay += sy;
    }
    for (; e < end; ++e) {
        float2 v = bfpair(G[(size_t)srow[e] * 32 + lane]);
        ax += v.x;
        ay += v.y;
    }
    float s = dinv[node];
    float2 bv = ((const float2*)bias)[lane];
    float ox = ax * s + bv.x;
    float oy = ay * s + bv.y;
    if (RELU) { ox = fmaxf(ox, 0.f); oy = fmaxf(oy, 0.f); }
    float2 o = make_float2(ox, oy);
    unsigned long long p;
    __builtin_memcpy(&p, &o, 8);
    __builtin_nontemporal_store(p, (unsigned long long*)&((float2*)O)[(size_t)node * 32 + lane]);
}

extern "C" void kernel_launch(void* const* d_in, const int* in_sizes, int n_in,
                              void* d_out, int out_size, void* d_ws, size_t ws_size,
                              hipStream_t stream) {
    const float* x  = (const float*)d_in[0];
    const int*   ei = (const int*)d_in[1];   // int32
    const float* W1 = (const float*)d_in[2];
    const float* b1 = (const float*)d_in[3];
    const float* W2 = (const float*)d_in[4];
    const float* b2 = (const float*)d_in[5];
    float* out = (float*)d_out;

    int N = in_sizes[0] / 128;
    int E = in_sizes[1] / 2;
    const int* row = ei;       // edge_index[0]
    const int* col = ei + E;   // edge_index[1]

    // Workspace layout (all regions written before read each call)
    char* ws = (char*)d_ws;
    float* dinv   = (float*)(ws + 0x000000);             // 200 KB
    int*   rowptr = (int*)  (ws + 0x080000);             // 200 KB + 4
    int*   gcur   = (int*)  (ws + 0x0F9000);             // 1 KB
    unsigned short* srow = (unsigned short*)(ws + 0x100000);   // 1.6 MB
    unsigned short* g1 = (unsigned short*)(ws + 0x440000);     // 12.8 MB
    unsigned short* wth1 = (unsigned short*)(ws + 0x10C0000);  // 32 KB
    unsigned short* wtl1 = (unsigned short*)(ws + 0x10D0000);  // 32 KB
    unsigned short* wth2 = (unsigned short*)(ws + 0x10E0000);  // 16 KB
    unsigned short* wtl2 = (unsigned short*)(ws + 0x10F0000);  // 16 KB
    unsigned int* bpack = (unsigned int*)(ws + 0x1200000);     // 6.29 MB slack buckets
    unsigned short* g2 = (unsigned short*)(ws + 0x2C00000);    // 6.4 MB

    int NB_BKT  = (E + CHUNK - 1) / CHUNK;
    int NBUCKET = (N + 255) / 256;   // 196

    // ---- setup + CSR build (3 launches) ----
    setup<<<256, 128, 0, stream>>>(W1, wth1, wtl1, W2, wth2, wtl2, gcur);
    bucket_scatter<<<NB_BKT, 256, 0, stream>>>(row, col, gcur, bpack, E);
    bucket_csr<<<NBUCKET, 256, 0, stream>>>(bpack, gcur, rowptr, dinv, srow, N, E);

    int nb;
    // ---- layer 1 GEMM ----
    nb = (N + 63) / 64;  // 4 waves/block, 16 rows/wave
    gemm_mfma1<<<nb, 256, 0, stream>>>(x, wth1, wtl1, dinv, g1, N);
    // ---- fused layer-1 gather + layer-2 GEMM (h2 stays in LDS) ----
    nb = (N + 3) / 4;    // 4 nodes/block
    gather_gemm2<<<nb, 256, 0, stream>>>(rowptr, srow, (const unsigned int*)g1,
                                         dinv, b1, wth2, wtl2, g2, N);
    // ---- layer-2 gather ----
    nb = (N + 7) / 8;    // half-wave per node
    gather64<false><<<nb, 256, 0, stream>>>(rowptr, srow, (const unsigned int*)g2,
                                            dinv, b2, out, N);
}

// Round 13
// 210.226 us; speedup vs baseline: 1.1334x; 1.1334x over previous
//
#include <hip/hip_runtime.h>

// GCN 2-layer forward for MI355X.
// out = D^-1/2 (A+I) D^-1/2 (X W) + b, twice, relu between.
// g = (X W) * dinv ; tmp[c] = g[c] + sum_{e: col_e=c} g[row_e] ; out = tmp*dinv + b.
// R2: CSR gather. R4: g bf16. R5: MFMA split-bf16 GEMM. R6-R8: bucketed CSR build.
// R9: XCD slicing FAILED. R10: scalar-addressed gather. R11: bf16 h2, 2-MFMA gemm2.
// R12: LDS-fused gather+gemm2 FAILED (barrier couples waves + LDS conflicts) -> reverted.
// R13: predicated unroll-8 gather (clamp index, zero-mask invalid) -> kills the
//      serial dependent remainder tail (~7 x 400cy for half the waves).

constexpr int KD = 128;      // inner dim of both GEMMs (Fin = Fh = 128)
constexpr int CHUNK = 4096;  // edges per block in scatter pass
constexpr int BCAP = 6144;   // slack capacity per bucket (mean 4096, sigma ~64)

using short8  = __attribute__((ext_vector_type(8))) short;
using float4v = __attribute__((ext_vector_type(4))) float;

// ---------------- bf16 helpers (storage = ushort, math = fp32) ----------------

__device__ __forceinline__ unsigned short f2bf(float f) {
    unsigned int u = __float_as_uint(f);
    u = (u + 0x7fffu + ((u >> 16) & 1u)) >> 16;  // round-to-nearest-even
    return (unsigned short)u;
}

__device__ __forceinline__ float2 bfpair(unsigned int u) {
    float2 f;
    f.x = __uint_as_float(u << 16);          // low short = first feature
    f.y = __uint_as_float(u & 0xffff0000u);  // high short = second feature
    return f;
}

__device__ __forceinline__ unsigned int packbf(float x, float y) {
    return (unsigned int)f2bf(x) | ((unsigned int)f2bf(y) << 16);
}

// split x = hi + lo (both bf16); subtraction is exact, |err| ~ 2^-17 |x|
__device__ __forceinline__ void bfsplit(float x, unsigned short& h, unsigned short& l) {
    h = f2bf(x);
    float fh = __uint_as_float((unsigned int)h << 16);
    l = f2bf(x - fh);
}

// ---------------- setup: W transpose+split (both layers) + gcur init ----------
__global__ __launch_bounds__(128) void setup(const float* __restrict__ W1,
                                             unsigned short* __restrict__ Wth1,
                                             unsigned short* __restrict__ Wtl1,
                                             const float* __restrict__ W2,
                                             unsigned short* __restrict__ Wth2,
                                             unsigned short* __restrict__ Wtl2,
                                             int* __restrict__ gcur) {
    int b = blockIdx.x;
    int n = threadIdx.x;
    int k = b & 127;
    if (b == 0) {
        gcur[n] = n * BCAP;
        gcur[n + 128] = (n + 128) * BCAP;
    }
    if (b < 128) {
        float w = W1[k * 128 + n];
        unsigned short h, l;
        bfsplit(w, h, l);
        Wth1[n * KD + k] = h;
        Wtl1[n * KD + k] = l;
    } else if (n < 64) {
        float w = W2[k * 64 + n];
        unsigned short h, l;
        bfsplit(w, h, l);
        Wth2[n * KD + k] = h;
        Wtl2[n * KD + k] = l;
    }
}

// ---------------- CSR build ----------------

// Edge scatter into slack buckets (by col>>8). Packed record: (row<<16)|col.
__global__ __launch_bounds__(256) void bucket_scatter(const int* __restrict__ row,
                                                      const int* __restrict__ col,
                                                      int* gcur,
                                                      unsigned int* __restrict__ bpack,
                                                      int E) {
    __shared__ int lh[256];
    __shared__ int lbase[256];
    lh[threadIdx.x] = 0;
    __syncthreads();
    int base = blockIdx.x * CHUNK;
#pragma unroll
    for (int r = 0; r < CHUNK / 256; ++r) {
        int e = base + r * 256 + threadIdx.x;
        if (e < E) atomicAdd(&lh[col[e] >> 8], 1);
    }
    __syncthreads();
    int c0 = lh[threadIdx.x];
    lbase[threadIdx.x] = c0 ? atomicAdd(&gcur[threadIdx.x], c0) : 0;
    __syncthreads();
    lh[threadIdx.x] = 0;  // reuse as local running offset
    __syncthreads();
#pragma unroll
    for (int r = 0; r < CHUNK / 256; ++r) {
        int e = base + r * 256 + threadIdx.x;
        if (e < E) {
            int c = col[e];
            int b = c >> 8;
            int slot = lbase[b] + atomicAdd(&lh[b], 1);
            bpack[slot] = ((unsigned int)row[e] << 16) | (unsigned int)c;
        }
    }
}

// One block per bucket: recompute bucket-count scan in LDS, node hist -> scan
// -> rowptr/dinv/srow. Bucket-major + node-within-bucket order IS CSR order.
__global__ __launch_bounds__(256) void bucket_csr(const unsigned int* __restrict__ bpack,
                                                  const int* __restrict__ gcur,
                                                  int* __restrict__ rowptr,
                                                  float* __restrict__ dinv,
                                                  unsigned short* __restrict__ srow,
                                                  int N, int E) {
    __shared__ int s[256];
    __shared__ int lh[256];
    __shared__ int lcur[256];
    __shared__ int sh_bstart;
    int b = blockIdx.x;
    int t = threadIdx.x;
    int cntb = gcur[t] - t * BCAP;
    s[t] = cntb;
    __syncthreads();
    for (int off = 1; off < 256; off <<= 1) {
        int tv = (t >= off) ? s[t - off] : 0;
        __syncthreads();
        s[t] += tv;
        __syncthreads();
    }
    if (t == b) sh_bstart = s[t] - cntb;  // exclusive prefix of this bucket
    if (b == 0 && t == 0) rowptr[N] = E;
    lh[t] = 0;
    __syncthreads();
    int bstart = sh_bstart;
    int nE = gcur[b] - b * BCAP;
    int base = b * BCAP;
    for (int i = t; i < nE; i += 256)
        atomicAdd(&lh[bpack[base + i] & 255], 1);
    __syncthreads();
    int v = lh[t];
    s[t] = v;
    __syncthreads();
    for (int off = 1; off < 256; off <<= 1) {
        int tv = (t >= off) ? s[t - off] : 0;
        __syncthreads();
        s[t] += tv;
        __syncthreads();
    }
    int myStart = bstart + s[t] - v;  // exclusive
    int node = (b << 8) + t;
    if (node < N) {
        rowptr[node] = myStart;
        dinv[node] = rsqrtf(1.0f + (float)v);
    }
    lcur[t] = myStart;
    __syncthreads();
    for (int i = t; i < nE; i += 256) {
        unsigned int p = bpack[base + i];
        int slot = atomicAdd(&lcur[p & 255], 1);
        srow[slot] = (unsigned short)(p >> 16);
    }
}

// -------- layer-1 GEMM (fp32 in): G = bf16(dinv*(X@W)), split A, 3 MFMAs -----
__global__ __launch_bounds__(256) void gemm_mfma1(const float* __restrict__ X,
                                                  const unsigned short* __restrict__ Wth,
                                                  const unsigned short* __restrict__ Wtl,
                                                  const float* __restrict__ dinv,
                                                  unsigned short* __restrict__ G, int N) {
    constexpr int FOUT = 128, NT = 8;
    int wave = threadIdx.x >> 6;
    int lane = threadIdx.x & 63;
    int row0 = (blockIdx.x * 4 + wave) * 16;
    if (row0 >= N) return;
    int m = lane & 15;
    int quad = lane >> 4;

    float4v acc[NT];
#pragma unroll
    for (int ct = 0; ct < NT; ++ct) acc[ct] = (float4v){0.f, 0.f, 0.f, 0.f};

    const float* xrow = X + (size_t)(row0 + m) * KD + quad * 8;

#pragma unroll
    for (int ks = 0; ks < 4; ++ks) {
        float4 xa = *(const float4*)(xrow + ks * 32);
        float4 xb = *(const float4*)(xrow + ks * 32 + 4);
        float xs[8] = {xa.x, xa.y, xa.z, xa.w, xb.x, xb.y, xb.z, xb.w};
        short8 ah, al;
#pragma unroll
        for (int j = 0; j < 8; ++j) {
            unsigned short h, l;
            bfsplit(xs[j], h, l);
            ah[j] = (short)h;
            al[j] = (short)l;
        }
        int koff = ks * 32 + quad * 8;
#pragma unroll
        for (int ct = 0; ct < NT; ++ct) {
            const unsigned short* wb = Wth + (size_t)(ct * 16 + m) * KD + koff;
            const unsigned short* wl = Wtl + (size_t)(ct * 16 + m) * KD + koff;
            short8 bh = *(const short8*)wb;
            short8 bl = *(const short8*)wl;
            acc[ct] = __builtin_amdgcn_mfma_f32_16x16x32_bf16(ah, bh, acc[ct], 0, 0, 0);
            acc[ct] = __builtin_amdgcn_mfma_f32_16x16x32_bf16(al, bh, acc[ct], 0, 0, 0);
            acc[ct] = __builtin_amdgcn_mfma_f32_16x16x32_bf16(ah, bl, acc[ct], 0, 0, 0);
        }
    }

#pragma unroll
    for (int r = 0; r < 4; ++r) {
        int row = row0 + quad * 4 + r;
        float s = dinv[row];
#pragma unroll
        for (int ct = 0; ct < NT; ++ct) {
            G[(size_t)row * FOUT + ct * 16 + m] = f2bf(acc[ct][r] * s);
        }
    }
}

// -------- layer-2 GEMM (bf16 in): G = bf16(dinv*(H@W)), 2 MFMAs, no A-split --
__global__ __launch_bounds__(256) void gemm_mfma2(const unsigned short* __restrict__ H,
                                                  const unsigned short* __restrict__ Wth,
                                                  const unsigned short* __restrict__ Wtl,
                                                  const float* __restrict__ dinv,
                                                  unsigned short* __restrict__ G, int N) {
    constexpr int FOUT = 64, NT = 4;
    int wave = threadIdx.x >> 6;
    int lane = threadIdx.x & 63;
    int row0 = (blockIdx.x * 4 + wave) * 16;
    if (row0 >= N) return;
    int m = lane & 15;
    int quad = lane >> 4;

    float4v acc[NT];
#pragma unroll
    for (int ct = 0; ct < NT; ++ct) acc[ct] = (float4v){0.f, 0.f, 0.f, 0.f};

    const unsigned short* hrow = H + (size_t)(row0 + m) * KD + quad * 8;

#pragma unroll
    for (int ks = 0; ks < 4; ++ks) {
        short8 a = *(const short8*)(hrow + ks * 32);
        int koff = ks * 32 + quad * 8;
#pragma unroll
        for (int ct = 0; ct < NT; ++ct) {
            short8 bh = *(const short8*)(Wth + (size_t)(ct * 16 + m) * KD + koff);
            short8 bl = *(const short8*)(Wtl + (size_t)(ct * 16 + m) * KD + koff);
            acc[ct] = __builtin_amdgcn_mfma_f32_16x16x32_bf16(a, bh, acc[ct], 0, 0, 0);
            acc[ct] = __builtin_amdgcn_mfma_f32_16x16x32_bf16(a, bl, acc[ct], 0, 0, 0);
        }
    }

#pragma unroll
    for (int r = 0; r < 4; ++r) {
        int row = row0 + quad * 4 + r;
        float s = dinv[row];
#pragma unroll
        for (int ct = 0; ct < 4; ++ct) {
            G[(size_t)row * FOUT + ct * 16 + m] = f2bf(acc[ct][r] * s);
        }
    }
}

// ---------------- CSR gather + finalize (fused), bf16 operand ----------------
// F=128: one wave per node, scalar (readfirstlane) row base. Predicated
// unroll-8: indices clamped (uniform), invalid slots zero-masked (bf16 pair
// 0x00000000 == +0,+0) -> no serial remainder tail, all loads issue together.
template <bool RELU>
__global__ __launch_bounds__(256) void gather128(const int* __restrict__ rowptr,
                                                 const unsigned short* __restrict__ srow,
                                                 const unsigned int* __restrict__ G,  // bf16x2
                                                 const float* __restrict__ dinv,
                                                 const float* __restrict__ bias,
                                                 unsigned int* __restrict__ H2,  // bf16x2 out
                                                 int N) {
    int node = (blockIdx.x * 256 + threadIdx.x) >> 6;
    int lane = threadIdx.x & 63;
    if (node >= N) return;
    int beg = rowptr[node];
    int end = rowptr[node + 1];

    float ax, ay;
    {
        float2 s0 = bfpair(G[(size_t)node * 64 + lane]);  // self-loop
        ax = s0.x; ay = s0.y;
    }

    for (int e = beg; e < end; e += 8) {
        unsigned int u[8];
#pragma unroll
        for (int j = 0; j < 8; ++j) {
            int idx = e + j;
            idx = (idx < end) ? idx : (end - 1);  // uniform clamp (end>beg here)
            int r = __builtin_amdgcn_readfirstlane((int)srow[idx]);
            const unsigned int* p = G + (size_t)r * 64;  // uniform base (SGPR)
            u[j] = p[lane];
        }
        float sx = 0.f, sy = 0.f;
#pragma unroll
        for (int j = 0; j < 8; ++j) {
            unsigned int uv = (e + j < end) ? u[j] : 0u;  // zero-mask invalid
            float2 v = bfpair(uv);
            sx += v.x; sy += v.y;
        }
        ax += sx; ay += sy;
    }
    float s = dinv[node];
    float2 bv = ((const float2*)bias)[lane];
    float ox = ax * s + bv.x;
    float oy = ay * s + bv.y;
    if (RELU) { ox = fmaxf(ox, 0.f); oy = fmaxf(oy, 0.f); }
    __builtin_nontemporal_store(packbf(ox, oy), &H2[(size_t)node * 64 + lane]);
}

// F=64: half-wave per node (32 lanes x bf16x2 = 128B row), predicated unroll-8,
// fp32 nt out. Conditions per-half-wave -> per-lane cndmask, no divergence cost.
template <bool RELU>
__global__ __launch_bounds__(256) void gather64(const int* __restrict__ rowptr,
                                                const unsigned short* __restrict__ srow,
                                                const unsigned int* __restrict__ G,  // bf16x2
                                                const float* __restrict__ dinv,
                                                const float* __restrict__ bias,
                                                float* __restrict__ O, int N) {
    int tid = blockIdx.x * 256 + threadIdx.x;
    int node = tid >> 5;          // half-wave per node
    int lane = threadIdx.x & 31;
    if (node >= N) return;
    int beg = rowptr[node];
    int end = rowptr[node + 1];

    float2 s0 = bfpair(G[(size_t)node * 32 + lane]);  // self-loop
    float ax = s0.x, ay = s0.y;

    for (int e = beg; e < end; e += 8) {
        unsigned int u[8];
#pragma unroll
        for (int j = 0; j < 8; ++j) {
            int idx = e + j;
            idx = (idx < end) ? idx : (end - 1);
            int r = (int)srow[idx];
            u[j] = G[(size_t)r * 32 + lane];
        }
        float sx = 0.f, sy = 0.f;
#pragma unroll
        for (int j = 0; j < 8; ++j) {
            unsigned int uv = (e + j < end) ? u[j] : 0u;
            float2 v = bfpair(uv);
            sx += v.x; sy += v.y;
        }
        ax += sx; ay += sy;
    }
    float s = dinv[node];
    float2 bv = ((const float2*)bias)[lane];
    float ox = ax * s + bv.x;
    float oy = ay * s + bv.y;
    if (RELU) { ox = fmaxf(ox, 0.f); oy = fmaxf(oy, 0.f); }
    float2 o = make_float2(ox, oy);
    unsigned long long p;
    __builtin_memcpy(&p, &o, 8);
    __builtin_nontemporal_store(p, (unsigned long long*)&((float2*)O)[(size_t)node * 32 + lane]);
}

extern "C" void kernel_launch(void* const* d_in, const int* in_sizes, int n_in,
                              void* d_out, int out_size, void* d_ws, size_t ws_size,
                              hipStream_t stream) {
    const float* x  = (const float*)d_in[0];
    const int*   ei = (const int*)d_in[1];   // int32
    const float* W1 = (const float*)d_in[2];
    const float* b1 = (const float*)d_in[3];
    const float* W2 = (const float*)d_in[4];
    const float* b2 = (const float*)d_in[5];
    float* out = (float*)d_out;

    int N = in_sizes[0] / 128;
    int E = in_sizes[1] / 2;
    const int* row = ei;       // edge_index[0]
    const int* col = ei + E;   // edge_index[1]

    // Workspace layout (all regions written before read each call)
    char* ws = (char*)d_ws;
    float* dinv   = (float*)(ws + 0x000000);             // 200 KB
    int*   rowptr = (int*)  (ws + 0x080000);             // 200 KB + 4
    int*   gcur   = (int*)  (ws + 0x0F9000);             // 1 KB
    unsigned short* srow = (unsigned short*)(ws + 0x100000);   // 1.6 MB
    unsigned short* g1 = (unsigned short*)(ws + 0x440000);     // 12.8 MB
    unsigned short* wth1 = (unsigned short*)(ws + 0x10C0000);  // 32 KB
    unsigned short* wtl1 = (unsigned short*)(ws + 0x10D0000);  // 32 KB
    unsigned short* wth2 = (unsigned short*)(ws + 0x10E0000);  // 16 KB
    unsigned short* wtl2 = (unsigned short*)(ws + 0x10F0000);  // 16 KB
    unsigned short* h2 = (unsigned short*)(ws + 0x1200000);    // 12.8 MB (bf16)
    unsigned short* g2 = (unsigned short*)(ws + 0x2C00000);    // 6.4 MB
    // Packed slack bucket buffer (256 x BCAP uints = 6.29 MB) overlaps h2's
    // region: consumed by bucket_csr before gather128 first writes h2.
    unsigned int* bpack = (unsigned int*)(ws + 0x1200000);     // 6.29 MB

    int NB_BKT  = (E + CHUNK - 1) / CHUNK;
    int NBUCKET = (N + 255) / 256;   // 196

    // ---- setup + CSR build (3 launches) ----
    setup<<<256, 128, 0, stream>>>(W1, wth1, wtl1, W2, wth2, wtl2, gcur);
    bucket_scatter<<<NB_BKT, 256, 0, stream>>>(row, col, gcur, bpack, E);
    bucket_csr<<<NBUCKET, 256, 0, stream>>>(bpack, gcur, rowptr, dinv, srow, N, E);

    int nb;
    // ---- layer 1 (F=128, relu) ----
    nb = (N + 63) / 64;  // 4 waves/block, 16 rows/wave
    gemm_mfma1<<<nb, 256, 0, stream>>>(x, wth1, wtl1, dinv, g1, N);
    nb = (N + 3) / 4;    // one wave per node
    gather128<true><<<nb, 256, 0, stream>>>(rowptr, srow, (const unsigned int*)g1,
                                            dinv, b1, (unsigned int*)h2, N);

    // ---- layer 2 (F=64, no relu) ----
    nb = (N + 63) / 64;
    gemm_mfma2<<<nb, 256, 0, stream>>>(h2, wth2, wtl2, dinv, g2, N);
    nb = (N + 7) / 8;    // half-wave per node
    gather64<false><<<nb, 256, 0, stream>>>(rowptr, srow, (const unsigned int*)g2,
                                            dinv, b2, out, N);
}

// Round 14
// 196.159 us; speedup vs baseline: 1.2147x; 1.0717x over previous
//
#include <hip/hip_runtime.h>

// GCN 2-layer forward for MI355X.
// out = D^-1/2 (A+I) D^-1/2 (X W) + b, twice, relu between.
// R2: CSR gather. R4: g bf16. R5: MFMA split-bf16 GEMM. R6-R8: bucketed CSR build.
// R9: XCD slicing FAILED. R10: scalar-addressed gather. R11: bf16 h2, 2-MFMA gemm2.
// R12: LDS-fused gather+gemm2 FAILED. R13: predicated unroll-8 gather (tail kill).
// R14: dinv deferred out of layer-1 GEMM (folded into gather128 as per-edge
//      scalar fma) -> gemm1 independent of CSR build -> merged into ONE launch
//      with bucket_csr (disjoint block ranges, CUs co-schedule latency-bound
//      CSR with MFMA GEMM). Scatter CHUNK 4096->2048 (2x blocks, was 3 waves/CU).

constexpr int KD = 128;      // inner dim of both GEMMs (Fin = Fh = 128)
constexpr int CHUNK = 2048;  // edges per block in scatter pass
constexpr int BCAP = 6144;   // slack capacity per bucket (mean 4096, sigma ~64)

using short8  = __attribute__((ext_vector_type(8))) short;
using float4v = __attribute__((ext_vector_type(4))) float;

// ---------------- bf16 helpers (storage = ushort, math = fp32) ----------------

__device__ __forceinline__ unsigned short f2bf(float f) {
    unsigned int u = __float_as_uint(f);
    u = (u + 0x7fffu + ((u >> 16) & 1u)) >> 16;  // round-to-nearest-even
    return (unsigned short)u;
}

__device__ __forceinline__ float2 bfpair(unsigned int u) {
    float2 f;
    f.x = __uint_as_float(u << 16);          // low short = first feature
    f.y = __uint_as_float(u & 0xffff0000u);  // high short = second feature
    return f;
}

__device__ __forceinline__ unsigned int packbf(float x, float y) {
    return (unsigned int)f2bf(x) | ((unsigned int)f2bf(y) << 16);
}

// split x = hi + lo (both bf16); subtraction is exact, |err| ~ 2^-17 |x|
__device__ __forceinline__ void bfsplit(float x, unsigned short& h, unsigned short& l) {
    h = f2bf(x);
    float fh = __uint_as_float((unsigned int)h << 16);
    l = f2bf(x - fh);
}

// ---------------- setup: W transpose+split (both layers) + gcur init ----------
__global__ __launch_bounds__(128) void setup(const float* __restrict__ W1,
                                             unsigned short* __restrict__ Wth1,
                                             unsigned short* __restrict__ Wtl1,
                                             const float* __restrict__ W2,
                                             unsigned short* __restrict__ Wth2,
                                             unsigned short* __restrict__ Wtl2,
                                             int* __restrict__ gcur) {
    int b = blockIdx.x;
    int n = threadIdx.x;
    int k = b & 127;
    if (b == 0) {
        gcur[n] = n * BCAP;
        gcur[n + 128] = (n + 128) * BCAP;
    }
    if (b < 128) {
        float w = W1[k * 128 + n];
        unsigned short h, l;
        bfsplit(w, h, l);
        Wth1[n * KD + k] = h;
        Wtl1[n * KD + k] = l;
    } else if (n < 64) {
        float w = W2[k * 64 + n];
        unsigned short h, l;
        bfsplit(w, h, l);
        Wth2[n * KD + k] = h;
        Wtl2[n * KD + k] = l;
    }
}

// ---------------- CSR build: edge scatter into slack buckets ----------------
// Packed record: (row<<16)|col (both < 50000 < 2^16).
__global__ __launch_bounds__(256) void bucket_scatter(const int* __restrict__ row,
                                                      const int* __restrict__ col,
                                                      int* gcur,
                                                      unsigned int* __restrict__ bpack,
                                                      int E) {
    __shared__ int lh[256];
    __shared__ int lbase[256];
    lh[threadIdx.x] = 0;
    __syncthreads();
    int base = blockIdx.x * CHUNK;
#pragma unroll
    for (int r = 0; r < CHUNK / 256; ++r) {
        int e = base + r * 256 + threadIdx.x;
        if (e < E) atomicAdd(&lh[col[e] >> 8], 1);
    }
    __syncthreads();
    int c0 = lh[threadIdx.x];
    lbase[threadIdx.x] = c0 ? atomicAdd(&gcur[threadIdx.x], c0) : 0;
    __syncthreads();
    lh[threadIdx.x] = 0;  // reuse as local running offset
    __syncthreads();
#pragma unroll
    for (int r = 0; r < CHUNK / 256; ++r) {
        int e = base + r * 256 + threadIdx.x;
        if (e < E) {
            int c = col[e];
            int b = c >> 8;
            int slot = lbase[b] + atomicAdd(&lh[b], 1);
            bpack[slot] = ((unsigned int)row[e] << 16) | (unsigned int)c;
        }
    }
}

// ------- MERGED: bucket_csr (blocks [0,NBUCKET)) + layer-1 GEMM (rest) -------
// CSR side: per-bucket LDS scan of bucket counts -> node hist -> scan ->
// rowptr/dinv/srow (bucket-major IS CSR order).
// GEMM side: G1 = bf16(X@W1)  -- NO dinv (deferred into gather128), so this
// half has no dependency on the CSR half and the CUs co-schedule both.
__global__ __launch_bounds__(256) void csr_and_gemm1(
        const unsigned int* __restrict__ bpack, const int* __restrict__ gcur,
        int* __restrict__ rowptr, float* __restrict__ dinv,
        unsigned short* __restrict__ srow, int N, int E, int NBUCKET,
        const float* __restrict__ X,
        const unsigned short* __restrict__ Wth,
        const unsigned short* __restrict__ Wtl,
        unsigned short* __restrict__ G) {
    __shared__ int s[256];
    __shared__ int lh[256];
    __shared__ int lcur[256];
    __shared__ int sh_bstart;

    if ((int)blockIdx.x < NBUCKET) {
        // ---------------- CSR build ----------------
        int b = blockIdx.x;
        int t = threadIdx.x;
        int cntb = gcur[t] - t * BCAP;
        s[t] = cntb;
        __syncthreads();
        for (int off = 1; off < 256; off <<= 1) {
            int tv = (t >= off) ? s[t - off] : 0;
            __syncthreads();
            s[t] += tv;
            __syncthreads();
        }
        if (t == b) sh_bstart = s[t] - cntb;  // exclusive prefix of this bucket
        if (b == 0 && t == 0) rowptr[N] = E;
        lh[t] = 0;
        __syncthreads();
        int bstart = sh_bstart;
        int nE = gcur[b] - b * BCAP;
        int base = b * BCAP;
        for (int i = t; i < nE; i += 256)
            atomicAdd(&lh[bpack[base + i] & 255], 1);
        __syncthreads();
        int v = lh[t];
        s[t] = v;
        __syncthreads();
        for (int off = 1; off < 256; off <<= 1) {
            int tv = (t >= off) ? s[t - off] : 0;
            __syncthreads();
            s[t] += tv;
            __syncthreads();
        }
        int myStart = bstart + s[t] - v;  // exclusive
        int node = (b << 8) + t;
        if (node < N) {
            rowptr[node] = myStart;
            dinv[node] = rsqrtf(1.0f + (float)v);
        }
        lcur[t] = myStart;
        __syncthreads();
        for (int i = t; i < nE; i += 256) {
            unsigned int p = bpack[base + i];
            int slot = atomicAdd(&lcur[p & 255], 1);
            srow[slot] = (unsigned short)(p >> 16);
        }
    } else {
        // ---------------- layer-1 GEMM (split-A, 3 MFMAs, no dinv) ----------
        constexpr int FOUT = 128, NT = 8;
        int wave = threadIdx.x >> 6;
        int lane = threadIdx.x & 63;
        int row0 = (((int)blockIdx.x - NBUCKET) * 4 + wave) * 16;
        if (row0 >= N) return;
        int m = lane & 15;
        int quad = lane >> 4;

        float4v acc[NT];
#pragma unroll
        for (int ct = 0; ct < NT; ++ct) acc[ct] = (float4v){0.f, 0.f, 0.f, 0.f};

        const float* xrow = X + (size_t)(row0 + m) * KD + quad * 8;

#pragma unroll
        for (int ks = 0; ks < 4; ++ks) {
            float4 xa = *(const float4*)(xrow + ks * 32);
            float4 xb = *(const float4*)(xrow + ks * 32 + 4);
            float xs[8] = {xa.x, xa.y, xa.z, xa.w, xb.x, xb.y, xb.z, xb.w};
            short8 ah, al;
#pragma unroll
            for (int j = 0; j < 8; ++j) {
                unsigned short h, l;
                bfsplit(xs[j], h, l);
                ah[j] = (short)h;
                al[j] = (short)l;
            }
            int koff = ks * 32 + quad * 8;
#pragma unroll
            for (int ct = 0; ct < NT; ++ct) {
                short8 bh = *(const short8*)(Wth + (size_t)(ct * 16 + m) * KD + koff);
                short8 bl = *(const short8*)(Wtl + (size_t)(ct * 16 + m) * KD + koff);
                acc[ct] = __builtin_amdgcn_mfma_f32_16x16x32_bf16(ah, bh, acc[ct], 0, 0, 0);
                acc[ct] = __builtin_amdgcn_mfma_f32_16x16x32_bf16(al, bh, acc[ct], 0, 0, 0);
                acc[ct] = __builtin_amdgcn_mfma_f32_16x16x32_bf16(ah, bl, acc[ct], 0, 0, 0);
            }
        }

#pragma unroll
        for (int r = 0; r < 4; ++r) {
            int row = row0 + quad * 4 + r;
#pragma unroll
            for (int ct = 0; ct < NT; ++ct) {
                G[(size_t)row * FOUT + ct * 16 + m] = f2bf(acc[ct][r]);
            }
        }
    }
}

// -------- layer-2 GEMM (bf16 in): G = bf16(dinv*(H@W)), 2 MFMAs, no A-split --
__global__ __launch_bounds__(256) void gemm_mfma2(const unsigned short* __restrict__ H,
                                                  const unsigned short* __restrict__ Wth,
                                                  const unsigned short* __restrict__ Wtl,
                                                  const float* __restrict__ dinv,
                                                  unsigned short* __restrict__ G, int N) {
    constexpr int FOUT = 64, NT = 4;
    int wave = threadIdx.x >> 6;
    int lane = threadIdx.x & 63;
    int row0 = (blockIdx.x * 4 + wave) * 16;
    if (row0 >= N) return;
    int m = lane & 15;
    int quad = lane >> 4;

    float4v acc[NT];
#pragma unroll
    for (int ct = 0; ct < NT; ++ct) acc[ct] = (float4v){0.f, 0.f, 0.f, 0.f};

    const unsigned short* hrow = H + (size_t)(row0 + m) * KD + quad * 8;

#pragma unroll
    for (int ks = 0; ks < 4; ++ks) {
        short8 a = *(const short8*)(hrow + ks * 32);
        int koff = ks * 32 + quad * 8;
#pragma unroll
        for (int ct = 0; ct < NT; ++ct) {
            short8 bh = *(const short8*)(Wth + (size_t)(ct * 16 + m) * KD + koff);
            short8 bl = *(const short8*)(Wtl + (size_t)(ct * 16 + m) * KD + koff);
            acc[ct] = __builtin_amdgcn_mfma_f32_16x16x32_bf16(a, bh, acc[ct], 0, 0, 0);
            acc[ct] = __builtin_amdgcn_mfma_f32_16x16x32_bf16(a, bl, acc[ct], 0, 0, 0);
        }
    }

#pragma unroll
    for (int r = 0; r < 4; ++r) {
        int row = row0 + quad * 4 + r;
        float s = dinv[row];
#pragma unroll
        for (int ct = 0; ct < 4; ++ct) {
            G[(size_t)row * FOUT + ct * 16 + m] = f2bf(acc[ct][r] * s);
        }
    }
}

// ---------------- CSR gather + finalize (fused), bf16 operand ----------------
// F=128: one wave per node, scalar (readfirstlane) row base, predicated
// unroll-8 (no serial tail). dinv[r] folded in as wave-uniform scalar fma
// (g1 is UNSCALED; see R14 note). tmp = dinv[n]*g1'[n] + sum dinv[r]*g1'[r];
// out = tmp*dinv[n] + b.
template <bool RELU>
__global__ __launch_bounds__(256) void gather128(const int* __restrict__ rowptr,
                                                 const unsigned short* __restrict__ srow,
                                                 const unsigned int* __restrict__ G,  // bf16x2
                                                 const float* __restrict__ dinv,
                                                 const float* __restrict__ bias,
                                                 unsigned int* __restrict__ H2,  // bf16x2 out
                                                 int N) {
    int node = (blockIdx.x * 256 + threadIdx.x) >> 6;
    int lane = threadIdx.x & 63;
    if (node >= N) return;
    int beg = rowptr[node];
    int end = rowptr[node + 1];
    float dn = dinv[node];

    float ax, ay;
    {
        float2 s0 = bfpair(G[(size_t)node * 64 + lane]);  // self-loop (x dinv[n])
        ax = s0.x * dn; ay = s0.y * dn;
    }

    for (int e = beg; e < end; e += 8) {
        unsigned int u[8];
        float dr[8];
#pragma unroll
        for (int j = 0; j < 8; ++j) {
            int idx = e + j;
            idx = (idx < end) ? idx : (end - 1);  // uniform clamp (end>beg here)
            int r = __builtin_amdgcn_readfirstlane((int)srow[idx]);
            dr[j] = dinv[r];                      // uniform scalar load
            const unsigned int* p = G + (size_t)r * 64;  // uniform base (SGPR)
            u[j] = p[lane];
        }
        float sx = 0.f, sy = 0.f;
#pragma unroll
        for (int j = 0; j < 8; ++j) {
            unsigned int uv = (e + j < end) ? u[j] : 0u;  // zero-mask invalid
            float2 v = bfpair(uv);
            sx = fmaf(dr[j], v.x, sx);
            sy = fmaf(dr[j], v.y, sy);
        }
        ax += sx; ay += sy;
    }
    float2 bv = ((const float2*)bias)[lane];
    float ox = ax * dn + bv.x;
    float oy = ay * dn + bv.y;
    if (RELU) { ox = fmaxf(ox, 0.f); oy = fmaxf(oy, 0.f); }
    __builtin_nontemporal_store(packbf(ox, oy), &H2[(size_t)node * 64 + lane]);
}

// F=64: half-wave per node (32 lanes x bf16x2 = 128B row), predicated unroll-8,
// fp32 nt out. g2 is pre-scaled by dinv (gemm2 epilogue), standard form.
template <bool RELU>
__global__ __launch_bounds__(256) void gather64(const int* __restrict__ rowptr,
                                                const unsigned short* __restrict__ srow,
                                                const unsigned int* __restrict__ G,  // bf16x2
                                                const float* __restrict__ dinv,
                                                const float* __restrict__ bias,
                                                float* __restrict__ O, int N) {
    int tid = blockIdx.x * 256 + threadIdx.x;
    int node = tid >> 5;          // half-wave per node
    int lane = threadIdx.x & 31;
    if (node >= N) return;
    int beg = rowptr[node];
    int end = rowptr[node + 1];

    float2 s0 = bfpair(G[(size_t)node * 32 + lane]);  // self-loop
    float ax = s0.x, ay = s0.y;

    for (int e = beg; e < end; e += 8) {
        unsigned int u[8];
#pragma unroll
        for (int j = 0; j < 8; ++j) {
            int idx = e + j;
            idx = (idx < end) ? idx : (end - 1);
            int r = (int)srow[idx];
            u[j] = G[(size_t)r * 32 + lane];
        }
        float sx = 0.f, sy = 0.f;
#pragma unroll
        for (int j = 0; j < 8; ++j) {
            unsigned int uv = (e + j < end) ? u[j] : 0u;
            float2 v = bfpair(uv);
            sx += v.x; sy += v.y;
        }
        ax += sx; ay += sy;
    }
    float s = dinv[node];
    float2 bv = ((const float2*)bias)[lane];
    float ox = ax * s + bv.x;
    float oy = ay * s + bv.y;
    if (RELU) { ox = fmaxf(ox, 0.f); oy = fmaxf(oy, 0.f); }
    float2 o = make_float2(ox, oy);
    unsigned long long p;
    __builtin_memcpy(&p, &o, 8);
    __builtin_nontemporal_store(p, (unsigned long long*)&((float2*)O)[(size_t)node * 32 + lane]);
}

extern "C" void kernel_launch(void* const* d_in, const int* in_sizes, int n_in,
                              void* d_out, int out_size, void* d_ws, size_t ws_size,
                              hipStream_t stream) {
    const float* x  = (const float*)d_in[0];
    const int*   ei = (const int*)d_in[1];   // int32
    const float* W1 = (const float*)d_in[2];
    const float* b1 = (const float*)d_in[3];
    const float* W2 = (const float*)d_in[4];
    const float* b2 = (const float*)d_in[5];
    float* out = (float*)d_out;

    int N = in_sizes[0] / 128;
    int E = in_sizes[1] / 2;
    const int* row = ei;       // edge_index[0]
    const int* col = ei + E;   // edge_index[1]

    // Workspace layout (all regions written before read each call)
    char* ws = (char*)d_ws;
    float* dinv   = (float*)(ws + 0x000000);             // 200 KB
    int*   rowptr = (int*)  (ws + 0x080000);             // 200 KB + 4
    int*   gcur   = (int*)  (ws + 0x0F9000);             // 1 KB
    unsigned short* srow = (unsigned short*)(ws + 0x100000);   // 1.6 MB
    unsigned short* g1 = (unsigned short*)(ws + 0x440000);     // 12.8 MB
    unsigned short* wth1 = (unsigned short*)(ws + 0x10C0000);  // 32 KB
    unsigned short* wtl1 = (unsigned short*)(ws + 0x10D0000);  // 32 KB
    unsigned short* wth2 = (unsigned short*)(ws + 0x10E0000);  // 16 KB
    unsigned short* wtl2 = (unsigned short*)(ws + 0x10F0000);  // 16 KB
    unsigned short* h2 = (unsigned short*)(ws + 0x1200000);    // 12.8 MB (bf16)
    unsigned short* g2 = (unsigned short*)(ws + 0x2C00000);    // 6.4 MB
    // Packed slack bucket buffer (256 x BCAP uints = 6.29 MB) overlaps h2's
    // region: consumed by csr_and_gemm1 before gather128 first writes h2.
    unsigned int* bpack = (unsigned int*)(ws + 0x1200000);     // 6.29 MB

    int NB_BKT  = (E + CHUNK - 1) / CHUNK;   // 391
    int NBUCKET = (N + 255) / 256;           // 196
    int NB_GEMM1 = (N + 63) / 64;            // 782

    // ---- setup + scatter + merged CSR/GEMM1 (3 launches) ----
    setup<<<256, 128, 0, stream>>>(W1, wth1, wtl1, W2, wth2, wtl2, gcur);
    bucket_scatter<<<NB_BKT, 256, 0, stream>>>(row, col, gcur, bpack, E);
    csr_and_gemm1<<<NBUCKET + NB_GEMM1, 256, 0, stream>>>(
        bpack, gcur, rowptr, dinv, srow, N, E, NBUCKET, x, wth1, wtl1, g1);

    int nb;
    // ---- layer-1 gather (dinv folded in) ----
    nb = (N + 3) / 4;    // one wave per node
    gather128<true><<<nb, 256, 0, stream>>>(rowptr, srow, (const unsigned int*)g1,
                                            dinv, b1, (unsigned int*)h2, N);

    // ---- layer 2 (F=64, no relu) ----
    nb = (N + 63) / 64;
    gemm_mfma2<<<nb, 256, 0, stream>>>(h2, wth2, wtl2, dinv, g2, N);
    nb = (N + 7) / 8;    // half-wave per node
    gather64<false><<<nb, 256, 0, stream>>>(rowptr, srow, (const unsigned int*)g2,
                                            dinv, b2, out, N);
}